// Round 7
// baseline (352.244 us; speedup 1.0000x reference)
//
#include <hip/hip_runtime.h>
#include <math.h>

#define HH 512
#define WW 512
#define NPIX (HH*WW)
#define NB 32
#define NS 21           // 2*MS+1 shifts per axis
#define KWIN 492        // window size (H - 2*10)
#define PADW 544        // padded template row stride (floats, 16B-aligned)
#define PADH 532        // padded template rows

// ---------------- Kernel W1a: interior column sums + template prep ----------
// blocks 0..255:   (b, ygroup of 59 rows) -> fp32 atomicAdd into I1/I2[b][x]
// blocks 256..263: template 64-row group -> atomicAdd sum1[32], sum2[32]
// blocks 264..795: build padded template row (circular halo both axes)
__global__ __launch_bounds__(256) void colsum_phase1(
    const float* __restrict__ fr, const float* __restrict__ tpl,
    float* __restrict__ I1, float* __restrict__ I2,
    double* __restrict__ sum1, double* __restrict__ sum2,
    float* __restrict__ tpl_pad)
{
    int blk = blockIdx.x;
    int t   = threadIdx.x;
    if (blk < 256) {
        int b  = blk >> 3;
        int yg = blk & 7;
        int y0 = 20 + 59 * yg;
        const float* img = fr + (size_t)b * NPIX;
        int xa = t, xb = t + 256;
        float s1a = 0.f, s2a = 0.f, s1b = 0.f, s2b = 0.f;
        for (int y = y0; y < y0 + 59; ++y) {
            float va = img[(size_t)y * WW + xa];
            float vb = img[(size_t)y * WW + xb];
            s1a += va; s2a += va * va;
            s1b += vb; s2b += vb * vb;
        }
        atomicAdd(&I1[b * WW + xa], s1a); atomicAdd(&I2[b * WW + xa], s2a);
        atomicAdd(&I1[b * WW + xb], s1b); atomicAdd(&I2[b * WW + xb], s2b);
    } else if (blk < 264) {
        int gq = blk - 256;            // rows [64gq, 64gq+64)
        int y0 = 64 * gq;
        int xa = t, xb = t + 256;
        float s1a = 0.f, s2a = 0.f, s1b = 0.f, s2b = 0.f;
        for (int y = y0; y < y0 + 64; ++y) {
            float va = tpl[(size_t)y * WW + xa];
            float vb = tpl[(size_t)y * WW + xb];
            s1a += va; s2a += va * va;
            s1b += vb; s2b += vb * vb;
        }
        double d1 = (double)s1a + (double)s1b;
        double d2 = (double)s2a + (double)s2b;
        for (int off = 32; off; off >>= 1) {
            d1 += __shfl_down(d1, off);
            d2 += __shfl_down(d2, off);
        }
        __shared__ double r1[4], r2[4];
        int lane = t & 63, wv = t >> 6;
        if (lane == 0) { r1[wv] = d1; r2[wv] = d2; }
        __syncthreads();
        if (t == 0) {
            atomicAdd(&sum1[32], r1[0] + r1[1] + r1[2] + r1[3]);
            atomicAdd(&sum2[32], r2[0] + r2[1] + r2[2] + r2[3]);
        }
    } else {
        int pr = blk - 264;            // 0..531 ; source row (pr-10) mod 512
        int sy = (pr - 10 + 512) & 511;
        const float* srow = tpl + (size_t)sy * WW;
        float* drow = tpl_pad + (size_t)pr * PADW;
        for (int c = t; c < PADW; c += 256) {
            int sx = (c - 10 + 512) & 511;     // padded col c <-> tpl x = c-10
            drow[c] = srow[sx];
        }
    }
}

// ---------------- Kernel W1b: edges + sliding windows + frame totals --------
__global__ __launch_bounds__(512) void colsum_combine(
    const float* __restrict__ fr, const float* __restrict__ I1,
    const float* __restrict__ I2, float* __restrict__ cs1,
    float* __restrict__ cs2, double* __restrict__ sum1)
{
    int b = blockIdx.x;
    int x = threadIdx.x;
    const float* img = fr + (size_t)b * NPIX;
    float top[20], bot[20];
#pragma unroll
    for (int y = 0; y < 20; ++y) top[y] = img[(size_t)y * WW + x];
#pragma unroll
    for (int y = 0; y < 20; ++y) bot[y] = img[(size_t)(492 + y) * WW + x];

    float t1 = 0.f, t2 = 0.f, b1 = 0.f, b2 = 0.f;
#pragma unroll
    for (int y = 0; y < 20; ++y) {
        t1 += top[y]; t2 += top[y] * top[y];
        b1 += bot[y]; b2 += bot[y] * bot[y];
    }
    float i1 = I1[b * WW + x], i2 = I2[b * WW + x];

    // frame total -> sum1[b]
    double tot = (double)i1 + (double)t1 + (double)b1;
    for (int off = 32; off; off >>= 1) tot += __shfl_down(tot, off);
    __shared__ double red[8];
    int lane = x & 63, wv = x >> 6;
    if (lane == 0) red[wv] = tot;
    __syncthreads();
    if (x == 0) {
        double s = 0.0;
        for (int i = 0; i < 8; ++i) s += red[i];
        sum1[b] = s;
    }

    // sliding windows: cs(u) = I + sum(top[u..19]) + sum(bot[0..u-1])
    float s1 = i1 + t1, s2 = i2 + t2;
    size_t base = (size_t)b * NS * WW + x;
    cs1[base] = s1; cs2[base] = s2;
#pragma unroll
    for (int u = 1; u < NS; ++u) {
        float a = top[u-1], c = bot[u-1];
        s1 += c - a;
        s2 += c * c - a * a;
        cs1[base + (size_t)u * WW] = s1;
        cs2[base + (size_t)u * WW] = s2;
    }
}

// ---------------- Kernel W2: window sums -> denominator (wave per triple) ---
__global__ __launch_bounds__(256) void denom_kernel(
    const float* __restrict__ cs1, const float* __restrict__ cs2,
    const double* __restrict__ sum1, const double* __restrict__ sum2,
    float* __restrict__ denom)
{
    int wid  = blockIdx.x * 4 + (threadIdx.x >> 6);   // one wave per (b,u,v)
    int lane = threadIdx.x & 63;
    if (wid >= NB * NS * NS) return;
    int v  = wid % NS;
    int bu = wid / NS;
    const float* r1 = cs1 + (size_t)bu * WW + v;
    const float* r2 = cs2 + (size_t)bu * WW + v;
    double s1 = 0.0, s2 = 0.0;
    for (int x = lane; x < KWIN; x += 64) { s1 += (double)r1[x]; s2 += (double)r2[x]; }
    for (int off = 32; off; off >>= 1) {
        s1 += __shfl_down(s1, off);
        s2 += __shfl_down(s2, off);
    }
    if (lane == 0) {
        const double inv = 1.0 / ((double)KWIN * (double)KWIN);
        double m1 = s1 * inv, m2 = s2 * inv;
        double var = m2 - (m1 * m1) * inv + 1e-8;   // reference's formula
        if (var < 0.0) var = 0.0;
        double tv = sum2[32] - sum1[32] * sum1[32] * (1.0 / (double)NPIX) + 1e-8;
        denom[wid] = (float)sqrt(tv * var);
    }
}

// ---------------- Kernel C: raw circular cross-correlation ------------------
// rawcc[b][u][v] = sum_{y,x} img[y,x] * tpl[(y-u+10)&511, (x-v+10)&511]
// u-TRIPLES per block. Padded template -> 21 aligned float4 L1 loads per row,
// all hoisted before the FMA block (single vmcnt wait). launch_bounds(256,1)
// gives the allocator a 512-VGPR budget: ~120 live regs, ZERO spill.
__global__ __launch_bounds__(256, 1) void corr_kernel(
    const float* __restrict__ fr, const float* __restrict__ tpl_pad,
    float* __restrict__ cc)
{
    int gid = blockIdx.x;          // 1792 blocks: b*56 + ug*8 + q
    int b   = gid / 56;
    int rem = gid % 56;
    int ug  = rem >> 3;            // 0..6  -> u0 = 3*ug
    int q   = rem & 7;
    int u0  = ug * 3;

    const int g  = threadIdx.x & 63;
    const int wv = threadIdx.x >> 6;
    const int x0 = g * 8;
    const int ystart = q * 64 + wv * 16;

    const float* img = fr + (size_t)b * NPIX;

    float acc[3][NS];
#pragma unroll
    for (int s = 0; s < 3; ++s)
#pragma unroll
        for (int v = 0; v < NS; ++v) acc[s][v] = 0.f;

    for (int y = ystart; y < ystart + 16; ++y) {
        const float* ip = img + (size_t)y * WW + x0;
        float4 i0 = *(const float4*)ip;
        float4 i1 = *(const float4*)(ip + 4);

        // hoist ALL template loads for this row (3 shifts x 7 float4)
        float w[3][28];
#pragma unroll
        for (int s = 0; s < 3; ++s) {
            const float* prow = tpl_pad + (size_t)(y - u0 - s + 20) * PADW + x0;
#pragma unroll
            for (int j = 0; j < 7; ++j) {
                float4 qv = *(const float4*)(prow + 4 * j);
                w[s][4*j] = qv.x; w[s][4*j+1] = qv.y; w[s][4*j+2] = qv.z; w[s][4*j+3] = qv.w;
            }
        }

        float im[8] = { i0.x, i0.y, i0.z, i0.w, i1.x, i1.y, i1.z, i1.w };
#pragma unroll
        for (int s = 0; s < 3; ++s) {
#pragma unroll
            for (int v = 0; v < NS; ++v) {
                float sv = acc[s][v];
#pragma unroll
                for (int p = 0; p < 8; ++p)
                    sv += im[p] * w[s][p + 20 - v];   // tpl x = x0+p+10-v
                acc[s][v] = sv;
            }
        }
    }

#pragma unroll
    for (int s = 0; s < 3; ++s)
#pragma unroll
        for (int v = 0; v < NS; ++v) {
            float tv = acc[s][v];
#pragma unroll
            for (int off = 32; off; off >>= 1) tv += __shfl_xor(tv, off);
            if (g == 0)
                atomicAdd(&cc[((size_t)b * NS + (u0 + s)) * NS + v], tv);
        }
}

// ---------------- Kernel S: argmax + log-parabola subpixel ------------------
__global__ __launch_bounds__(64) void argmax_kernel(
    const float* __restrict__ cc, const float* __restrict__ denom,
    const double* __restrict__ sum1, float* __restrict__ shifts)
{
    int b = blockIdx.x;
    const float* C = cc    + (size_t)b * NS * NS;
    const float* D = denom + (size_t)b * NS * NS;
    float corr = (float)(sum1[b] * sum1[32] * (1.0 / (double)NPIX));
    int l = threadIdx.x;
    float best = -1e30f; int bidx = NS * NS;
    for (int i = l; i < NS * NS; i += 64) {
        float v = fabsf(C[i] - corr) / D[i];
        if (v != v) v = 0.f;               // NaN -> 0 (matches reference)
        if (v > best) { best = v; bidx = i; }
    }
    for (int off = 32; off; off >>= 1) {
        float ov = __shfl_down(best, off);
        int   oi = __shfl_down(bidx, off);
        if (ov > best || (ov == best && oi < bidx)) { best = ov; bidx = oi; }
    }
    if (l == 0) {
        int shx = bidx / NS, shy = bidx % NS;
        auto nccAt = [&](int i, int j) -> float {
            i = (i < 0) ? i + NS : i; i = (i > NS - 1) ? NS - 1 : i;  // jnp wrap-then-clamp
            j = (j < 0) ? j + NS : j; j = (j > NS - 1) ? NS - 1 : j;
            float v = fabsf(C[i * NS + j] - corr) / D[i * NS + j];
            if (v != v) v = 0.f;
            return v;
        };
        float lc  = logf(nccAt(shx, shy));
        float lxm = logf(nccAt(shx - 1, shy));
        float lxp = logf(nccAt(shx + 1, shy));
        float lym = logf(nccAt(shx, shy - 1));
        float lyp = logf(nccAt(shx, shy + 1));
        float shxn = -(float)(shx - 10) - (lxm - lxp) / (2.f * lxm - 4.f * lc + 2.f * lxp);
        float shyn = -(float)(shy - 10) - (lym - lyp) / (2.f * lym - 4.f * lc + 2.f * lyp);
        shifts[b]      = shxn;   // dy
        shifts[32 + b] = shyn;   // dx
    }
}

// ---------------- Kernel B: bilinear warp + transposed write ----------------
__device__ __forceinline__ float samp(const float* __restrict__ img, int y, int x) {
    bool valid = (y >= 0) & (y < HH) & (x >= 0) & (x < WW);
    int yc = min(max(y, 0), HH - 1), xc = min(max(x, 0), WW - 1);
    float v = img[(size_t)yc * WW + xc];
    return valid ? v : 0.f;
}

__global__ __launch_bounds__(256) void warp_kernel(
    const float* __restrict__ fr, const float* __restrict__ shifts,
    float* __restrict__ out)
{
    int b  = blockIdx.z;
    int h0 = blockIdx.y * 32;
    int w0 = blockIdx.x * 32;
    float dy = shifts[b], dx = shifts[32 + b];
    const float* img = fr + (size_t)b * NPIX;
    __shared__ float tile[32][33];
    int tx = threadIdx.x & 31;
    int tz = threadIdx.x >> 5;
#pragma unroll
    for (int s = 0; s < 4; ++s) {
        int h = h0 + tz + 8 * s;
        int w = w0 + tx;
        float yq = (float)h - dy;
        float xq = (float)w - dx;
        float y0f = floorf(yq), x0f = floorf(xq);
        float wy = yq - y0f, wx = xq - x0f;
        int y0 = (int)y0f, x0 = (int)x0f;
        float v00 = samp(img, y0,     x0);
        float v01 = samp(img, y0,     x0 + 1);
        float v10 = samp(img, y0 + 1, x0);
        float v11 = samp(img, y0 + 1, x0 + 1);
        float val = v00 * (1.f - wy) * (1.f - wx) + v01 * (1.f - wy) * wx
                  + v10 * wy * (1.f - wx)         + v11 * wy * wx;
        tile[tz + 8 * s][tx] = val;
    }
    __syncthreads();
#pragma unroll
    for (int s = 0; s < 4; ++s) {
        int hh = tx;
        int ww = tz + 8 * s;
        out[(size_t)b * NPIX + (size_t)(w0 + ww) * HH + (h0 + hh)] = tile[hh][ww];
    }
}

// ---------------- launch ----------------------------------------------------
extern "C" void kernel_launch(void* const* d_in, const int* in_sizes, int n_in,
                              void* d_out, int out_size, void* d_ws, size_t ws_size,
                              hipStream_t stream) {
    const float* fr  = (const float*)d_in[0];   // (1,32,512,512,1) flat
    const float* tpl = (const float*)d_in[1];   // (512,512)
    float* out = (float*)d_out;
    char* ws = (char*)d_ws;

    // ws layout (~4.2 MB)
    double* sum1    = (double*)(ws + 0);          // 33 doubles
    double* sum2    = (double*)(ws + 512);        // 33 doubles
    float*  cc      = (float*) (ws + 4096);       // 32*441 floats
    float*  I1      = (float*) (ws + 61440);      // 32*512 floats
    float*  I2      = (float*) (ws + 126976);     // 32*512 floats
    float*  shifts  = (float*) (ws + 196608);     // 64 floats
    float*  denom   = (float*) (ws + 200704);     // 32*441 floats
    float*  cs1     = (float*) (ws + 262144);     // 32*21*512 floats
    float*  cs2     = (float*) (ws + 1638400);    // 32*21*512 floats
    float*  tpl_pad = (float*) (ws + 3014656);    // 532*544 floats (~1.16 MB)

    hipMemsetAsync(ws, 0, 192512, stream);       // zero sums + cc + I1/I2

    colsum_phase1 <<<796, 256, 0, stream>>>(fr, tpl, I1, I2, sum1, sum2, tpl_pad);
    colsum_combine<<<32, 512, 0, stream>>>(fr, I1, I2, cs1, cs2, sum1);
    denom_kernel  <<<(NB * NS * NS + 3) / 4, 256, 0, stream>>>(cs1, cs2, sum1, sum2, denom);
    corr_kernel   <<<1792, 256, 0, stream>>>(fr, tpl_pad, cc);
    argmax_kernel <<<32, 64, 0, stream>>>(cc, denom, sum1, shifts);
    warp_kernel   <<<dim3(16, 16, 32), 256, 0, stream>>>(fr, shifts, out);
}

// Round 8
// 212.863 us; speedup vs baseline: 1.6548x; 1.6548x over previous
//
#include <hip/hip_runtime.h>
#include <math.h>

#define HH 512
#define WW 512
#define NPIX (HH*WW)
#define NB 32
#define NS 21           // 2*MS+1 shifts per axis
#define KWIN 492        // window size (H - 2*10)

typedef __attribute__((ext_vector_type(8))) short short8;
typedef __attribute__((ext_vector_type(8))) unsigned short ushort8;
typedef __attribute__((ext_vector_type(4))) float floatx4;

__device__ __forceinline__ unsigned short f2bf(float f) {
    unsigned u = __float_as_uint(f);
    unsigned r = (u + 0x7fffu + ((u >> 16) & 1u)) >> 16;
    return (unsigned short)r;
}

// ---------------- Kernel W1a: interior column sums + template sums ----------
__global__ __launch_bounds__(256) void colsum_phase1(
    const float* __restrict__ fr, const float* __restrict__ tpl,
    float* __restrict__ I1, float* __restrict__ I2,
    double* __restrict__ sum1, double* __restrict__ sum2)
{
    int blk = blockIdx.x;
    int t   = threadIdx.x;
    if (blk < 256) {
        int b  = blk >> 3;
        int yg = blk & 7;
        int y0 = 20 + 59 * yg;
        const float* img = fr + (size_t)b * NPIX;
        int xa = t, xb = t + 256;
        float s1a = 0.f, s2a = 0.f, s1b = 0.f, s2b = 0.f;
        for (int y = y0; y < y0 + 59; ++y) {
            float va = img[(size_t)y * WW + xa];
            float vb = img[(size_t)y * WW + xb];
            s1a += va; s2a += va * va;
            s1b += vb; s2b += vb * vb;
        }
        atomicAdd(&I1[b * WW + xa], s1a); atomicAdd(&I2[b * WW + xa], s2a);
        atomicAdd(&I1[b * WW + xb], s1b); atomicAdd(&I2[b * WW + xb], s2b);
    } else {
        int gq = blk - 256;            // rows [64gq, 64gq+64)
        int y0 = 64 * gq;
        int xa = t, xb = t + 256;
        float s1a = 0.f, s2a = 0.f, s1b = 0.f, s2b = 0.f;
        for (int y = y0; y < y0 + 64; ++y) {
            float va = tpl[(size_t)y * WW + xa];
            float vb = tpl[(size_t)y * WW + xb];
            s1a += va; s2a += va * va;
            s1b += vb; s2b += vb * vb;
        }
        double d1 = (double)s1a + (double)s1b;
        double d2 = (double)s2a + (double)s2b;
        for (int off = 32; off; off >>= 1) {
            d1 += __shfl_down(d1, off);
            d2 += __shfl_down(d2, off);
        }
        __shared__ double r1[4], r2[4];
        int lane = t & 63, wv = t >> 6;
        if (lane == 0) { r1[wv] = d1; r2[wv] = d2; }
        __syncthreads();
        if (t == 0) {
            atomicAdd(&sum1[32], r1[0] + r1[1] + r1[2] + r1[3]);
            atomicAdd(&sum2[32], r2[0] + r2[1] + r2[2] + r2[3]);
        }
    }
}

// ---------------- Kernel W1b: edges + sliding windows + frame totals --------
__global__ __launch_bounds__(512) void colsum_combine(
    const float* __restrict__ fr, const float* __restrict__ I1,
    const float* __restrict__ I2, float* __restrict__ cs1,
    float* __restrict__ cs2, double* __restrict__ sum1)
{
    int b = blockIdx.x;
    int x = threadIdx.x;
    const float* img = fr + (size_t)b * NPIX;
    float top[20], bot[20];
#pragma unroll
    for (int y = 0; y < 20; ++y) top[y] = img[(size_t)y * WW + x];
#pragma unroll
    for (int y = 0; y < 20; ++y) bot[y] = img[(size_t)(492 + y) * WW + x];

    float t1 = 0.f, t2 = 0.f, b1 = 0.f, b2 = 0.f;
#pragma unroll
    for (int y = 0; y < 20; ++y) {
        t1 += top[y]; t2 += top[y] * top[y];
        b1 += bot[y]; b2 += bot[y] * bot[y];
    }
    float i1 = I1[b * WW + x], i2 = I2[b * WW + x];

    double tot = (double)i1 + (double)t1 + (double)b1;
    for (int off = 32; off; off >>= 1) tot += __shfl_down(tot, off);
    __shared__ double red[8];
    int lane = x & 63, wv = x >> 6;
    if (lane == 0) red[wv] = tot;
    __syncthreads();
    if (x == 0) {
        double s = 0.0;
        for (int i = 0; i < 8; ++i) s += red[i];
        sum1[b] = s;
    }

    float s1 = i1 + t1, s2 = i2 + t2;
    size_t base = (size_t)b * NS * WW + x;
    cs1[base] = s1; cs2[base] = s2;
#pragma unroll
    for (int u = 1; u < NS; ++u) {
        float a = top[u-1], c = bot[u-1];
        s1 += c - a;
        s2 += c * c - a * a;
        cs1[base + (size_t)u * WW] = s1;
        cs2[base + (size_t)u * WW] = s2;
    }
}

// ---------------- Kernel W2: window sums -> denominator (wave per triple) ---
__global__ __launch_bounds__(256) void denom_kernel(
    const float* __restrict__ cs1, const float* __restrict__ cs2,
    const double* __restrict__ sum1, const double* __restrict__ sum2,
    float* __restrict__ denom)
{
    int wid  = blockIdx.x * 4 + (threadIdx.x >> 6);   // one wave per (b,u,v)
    int lane = threadIdx.x & 63;
    if (wid >= NB * NS * NS) return;
    int v  = wid % NS;
    int bu = wid / NS;
    const float* r1 = cs1 + (size_t)bu * WW + v;
    const float* r2 = cs2 + (size_t)bu * WW + v;
    double s1 = 0.0, s2 = 0.0;
    for (int x = lane; x < KWIN; x += 64) { s1 += (double)r1[x]; s2 += (double)r2[x]; }
    for (int off = 32; off; off >>= 1) {
        s1 += __shfl_down(s1, off);
        s2 += __shfl_down(s2, off);
    }
    if (lane == 0) {
        const double inv = 1.0 / ((double)KWIN * (double)KWIN);
        double m1 = s1 * inv, m2 = s2 * inv;
        double var = m2 - (m1 * m1) * inv + 1e-8;   // reference's formula
        if (var < 0.0) var = 0.0;
        double tv = sum2[32] - sum1[32] * sum1[32] * (1.0 / (double)NPIX) + 1e-8;
        denom[wid] = (float)sqrt(tv * var);
    }
}

// ---------------- Prep A: frames fp32 -> bf16, interleaved [k/8][32][8] -----
__global__ __launch_bounds__(256) void conv_frames(
    const float* __restrict__ fr, unsigned short* __restrict__ frBi)
{
    int tid = blockIdx.x * 256 + threadIdx.x;   // 0..1048575 = kc8*32 + n
    int n   = tid & 31;
    int kc8 = tid >> 5;
    const float* src = fr + (size_t)n * NPIX + (size_t)kc8 * 8;
    float4 v0 = *(const float4*)src;
    float4 v1 = *(const float4*)(src + 4);
    ushort8 o;
    o[0] = f2bf(v0.x); o[1] = f2bf(v0.y); o[2] = f2bf(v0.z); o[3] = f2bf(v0.w);
    o[4] = f2bf(v1.x); o[5] = f2bf(v1.y); o[6] = f2bf(v1.z); o[7] = f2bf(v1.w);
    *(ushort8*)(frBi + (size_t)tid * 8) = o;
}

// ---------------- Prep B: 21 dv-shifted bf16 template copies ----------------
// tplv[dv][pr][x] = tpl[(pr-10)&511][(x-dv+10)&511]  -> A-loads 16B aligned
__global__ __launch_bounds__(256) void build_tplv(
    const float* __restrict__ tpl, unsigned short* __restrict__ tplv)
{
    int pr = blockIdx.x;        // 0..531
    int dv = blockIdx.y;        // 0..20
    int sy = (pr + 502) & 511;  // (pr-10) mod 512
    const float* srow = tpl + (size_t)sy * WW;
    unsigned short* drow = tplv + ((size_t)dv * 532 + pr) * 512;
    for (int x = threadIdx.x; x < 512; x += 256) {
        int sx = (x - dv + 522) & 511;   // (x - dv + 10) mod 512
        drow[x] = f2bf(srow[sx]);
    }
}

// ---------------- Kernel C: implicit-GEMM correlation via MFMA --------------
// C[m=(du,dv)][n=b] = sum_k T[(du,dv)][k] * I[k][b]; M=441 (28 16-tiles),
// N=32 (2 tiles), K=262144 split into 128 chunks of 2048.
// Wave = (m-pair mg2 in [0,14), k-chunk kb in [0,128)). A addr = laneConst+k,
// B addr = laneConstB+32k. 4 MFMA + 4 loads per k-step. fp32 atomics to cc.
__global__ __launch_bounds__(256) void corr_mfma(
    const unsigned short* __restrict__ frBi,
    const unsigned short* __restrict__ tplv,
    float* __restrict__ cc)
{
    const int l   = threadIdx.x & 63;
    const int wv  = threadIdx.x >> 6;
    const int wg  = blockIdx.x * 4 + wv;   // 0..1791
    const int mg2 = wg % 14;
    const int kb  = wg / 14;               // 0..127
    const int k0  = kb << 11;              // *2048
    const int kg  = l >> 4;                // k-group 0..3
    const int ln  = l & 15;

    const unsigned short* pA[2];
#pragma unroll
    for (int mt = 0; mt < 2; ++mt) {
        int m_g = 32 * mg2 + 16 * mt + ln;
        int du  = (m_g * 1561) >> 15;      // m_g/21 exact for m_g<=447
        int dv  = m_g - 21 * du;
        if (m_g >= 441) { du = 0; dv = 0; }   // pad rows: computed, never stored
        pA[mt] = tplv + ((size_t)(dv * 532 + 20 - du) * 512 + 8 * kg + k0);
    }
    const unsigned short* pB0 = frBi + ((size_t)k0 * 32 + kg * 256 + ln * 8);
    const unsigned short* pB1 = pB0 + 128;   // frames 16..31

    floatx4 acc00 = {}, acc01 = {}, acc10 = {}, acc11 = {};

#pragma unroll 4
    for (int ks = 0; ks < 64; ++ks) {
        short8 A0 = *(const short8*)pA[0];
        short8 A1 = *(const short8*)pA[1];
        short8 B0 = *(const short8*)pB0;
        short8 B1 = *(const short8*)pB1;
        acc00 = __builtin_amdgcn_mfma_f32_16x16x32_bf16(A0, B0, acc00, 0, 0, 0);
        acc01 = __builtin_amdgcn_mfma_f32_16x16x32_bf16(A0, B1, acc01, 0, 0, 0);
        acc10 = __builtin_amdgcn_mfma_f32_16x16x32_bf16(A1, B0, acc10, 0, 0, 0);
        acc11 = __builtin_amdgcn_mfma_f32_16x16x32_bf16(A1, B1, acc11, 0, 0, 0);
        pA[0] += 32; pA[1] += 32; pB0 += 1024; pB1 += 1024;
    }

    // C/D layout: col n = lane&15, row m = 4*(lane>>4)+reg (HW-verified)
#pragma unroll
    for (int r = 0; r < 4; ++r) {
        int mrow = 4 * kg + r;
        int m0 = 32 * mg2 + mrow;          // mt=0
        int m1 = m0 + 16;                  // mt=1
        int nA = ln;                       // nt=0
        int nBn = ln + 16;                 // nt=1
        if (m0 < 441) {
            atomicAdd(&cc[(size_t)nA  * 441 + m0], acc00[r]);
            atomicAdd(&cc[(size_t)nBn * 441 + m0], acc01[r]);
        }
        if (m1 < 441) {
            atomicAdd(&cc[(size_t)nA  * 441 + m1], acc10[r]);
            atomicAdd(&cc[(size_t)nBn * 441 + m1], acc11[r]);
        }
    }
}

// ---------------- Kernel S: argmax + log-parabola subpixel ------------------
__global__ __launch_bounds__(64) void argmax_kernel(
    const float* __restrict__ cc, const float* __restrict__ denom,
    const double* __restrict__ sum1, float* __restrict__ shifts)
{
    int b = blockIdx.x;
    const float* C = cc    + (size_t)b * NS * NS;
    const float* D = denom + (size_t)b * NS * NS;
    float corr = (float)(sum1[b] * sum1[32] * (1.0 / (double)NPIX));
    int l = threadIdx.x;
    float best = -1e30f; int bidx = NS * NS;
    for (int i = l; i < NS * NS; i += 64) {
        float v = fabsf(C[i] - corr) / D[i];
        if (v != v) v = 0.f;               // NaN -> 0 (matches reference)
        if (v > best) { best = v; bidx = i; }
    }
    for (int off = 32; off; off >>= 1) {
        float ov = __shfl_down(best, off);
        int   oi = __shfl_down(bidx, off);
        if (ov > best || (ov == best && oi < bidx)) { best = ov; bidx = oi; }
    }
    if (l == 0) {
        int shx = bidx / NS, shy = bidx % NS;
        auto nccAt = [&](int i, int j) -> float {
            i = (i < 0) ? i + NS : i; i = (i > NS - 1) ? NS - 1 : i;  // jnp wrap-then-clamp
            j = (j < 0) ? j + NS : j; j = (j > NS - 1) ? NS - 1 : j;
            float v = fabsf(C[i * NS + j] - corr) / D[i * NS + j];
            if (v != v) v = 0.f;
            return v;
        };
        float lc  = logf(nccAt(shx, shy));
        float lxm = logf(nccAt(shx - 1, shy));
        float lxp = logf(nccAt(shx + 1, shy));
        float lym = logf(nccAt(shx, shy - 1));
        float lyp = logf(nccAt(shx, shy + 1));
        float shxn = -(float)(shx - 10) - (lxm - lxp) / (2.f * lxm - 4.f * lc + 2.f * lxp);
        float shyn = -(float)(shy - 10) - (lym - lyp) / (2.f * lym - 4.f * lc + 2.f * lyp);
        shifts[b]      = shxn;   // dy
        shifts[32 + b] = shyn;   // dx
    }
}

// ---------------- Kernel B: bilinear warp + transposed write ----------------
__device__ __forceinline__ float samp(const float* __restrict__ img, int y, int x) {
    bool valid = (y >= 0) & (y < HH) & (x >= 0) & (x < WW);
    int yc = min(max(y, 0), HH - 1), xc = min(max(x, 0), WW - 1);
    float v = img[(size_t)yc * WW + xc];
    return valid ? v : 0.f;
}

__global__ __launch_bounds__(256) void warp_kernel(
    const float* __restrict__ fr, const float* __restrict__ shifts,
    float* __restrict__ out)
{
    int b  = blockIdx.z;
    int h0 = blockIdx.y * 32;
    int w0 = blockIdx.x * 32;
    float dy = shifts[b], dx = shifts[32 + b];
    const float* img = fr + (size_t)b * NPIX;
    __shared__ float tile[32][33];
    int tx = threadIdx.x & 31;
    int tz = threadIdx.x >> 5;
#pragma unroll
    for (int s = 0; s < 4; ++s) {
        int h = h0 + tz + 8 * s;
        int w = w0 + tx;
        float yq = (float)h - dy;
        float xq = (float)w - dx;
        float y0f = floorf(yq), x0f = floorf(xq);
        float wy = yq - y0f, wx = xq - x0f;
        int y0 = (int)y0f, x0 = (int)x0f;
        float v00 = samp(img, y0,     x0);
        float v01 = samp(img, y0,     x0 + 1);
        float v10 = samp(img, y0 + 1, x0);
        float v11 = samp(img, y0 + 1, x0 + 1);
        float val = v00 * (1.f - wy) * (1.f - wx) + v01 * (1.f - wy) * wx
                  + v10 * wy * (1.f - wx)         + v11 * wy * wx;
        tile[tz + 8 * s][tx] = val;
    }
    __syncthreads();
#pragma unroll
    for (int s = 0; s < 4; ++s) {
        int hh = tx;
        int ww = tz + 8 * s;
        out[(size_t)b * NPIX + (size_t)(w0 + ww) * HH + (h0 + hh)] = tile[hh][ww];
    }
}

// ---------------- launch ----------------------------------------------------
extern "C" void kernel_launch(void* const* d_in, const int* in_sizes, int n_in,
                              void* d_out, int out_size, void* d_ws, size_t ws_size,
                              hipStream_t stream) {
    const float* fr  = (const float*)d_in[0];   // (1,32,512,512,1) flat
    const float* tpl = (const float*)d_in[1];   // (512,512)
    float* out = (float*)d_out;
    char* ws = (char*)d_ws;

    // ws layout (~28.5 MB). frBi/tplv OVERLAY cs1/cs2 (consumed by denom first).
    double* sum1    = (double*)(ws + 0);          // 33 doubles
    double* sum2    = (double*)(ws + 512);        // 33 doubles
    float*  cc      = (float*) (ws + 4096);       // 32*441 floats
    float*  I1      = (float*) (ws + 61440);      // 32*512 floats
    float*  I2      = (float*) (ws + 126976);     // 32*512 floats
    float*  shifts  = (float*) (ws + 196608);     // 64 floats
    float*  denom   = (float*) (ws + 200704);     // 32*441 floats
    float*  cs1     = (float*) (ws + 262144);     // 32*21*512 floats
    float*  cs2     = (float*) (ws + 1638400);    // 32*21*512 floats
    unsigned short* frBi = (unsigned short*)(ws + 262144);    // 16.78 MB (after denom)
    unsigned short* tplv = (unsigned short*)(ws + 17039360);  // 11.44 MB

    hipMemsetAsync(ws, 0, 192512, stream);       // zero sums + cc + I1/I2

    colsum_phase1 <<<264, 256, 0, stream>>>(fr, tpl, I1, I2, sum1, sum2);
    colsum_combine<<<32, 512, 0, stream>>>(fr, I1, I2, cs1, cs2, sum1);
    denom_kernel  <<<(NB * NS * NS + 3) / 4, 256, 0, stream>>>(cs1, cs2, sum1, sum2, denom);
    // prep AFTER denom (frBi overlays cs1/cs2)
    conv_frames   <<<4096, 256, 0, stream>>>(fr, frBi);
    build_tplv    <<<dim3(532, 21), 256, 0, stream>>>(tpl, tplv);
    corr_mfma     <<<448, 256, 0, stream>>>(frBi, tplv, cc);
    argmax_kernel <<<32, 64, 0, stream>>>(cc, denom, sum1, shifts);
    warp_kernel   <<<dim3(16, 16, 32), 256, 0, stream>>>(fr, shifts, out);
}